// Round 5
// baseline (42.452 us; speedup 1.0000x reference)
//
#include <hip/hip_runtime.h>

// out[0] = mean(|pred - mask|) over 16Mi fp32 elements (the Gaussian-conv
// loop in the reference is dead code). Memory-bound streaming reduction.
//
// Round-5: main kernel identical to round-4 (6.4 TB/s effective, at the
// streaming floor). Tail overhead attack: drop the final_reduce dispatch;
// each block atomicAdds partial/N into out[0], which a 4-byte memsetAsync
// zeroes at the head of the graph. No device fences (round-3 lesson); float
// atomic order nondeterminism ~1e-7 << 6.7e-3 threshold.

#define N_TOTAL (16u * 1024u * 1024u)   // 16,777,216 elements
#define NTHREADS 256
#define NBLOCKS  2048
#define PER_THREAD 8
#define CHUNK (NTHREADS * PER_THREAD)   // 2048 float4 per block per input

__global__ __launch_bounds__(NTHREADS) void abs_diff_mean(
    const float4* __restrict__ pred,
    const float4* __restrict__ mask,
    float* __restrict__ out) {
    const unsigned base = blockIdx.x * CHUNK + threadIdx.x;

    float4 p[PER_THREAD], m[PER_THREAD];
    #pragma unroll
    for (int k = 0; k < PER_THREAD; ++k) p[k] = pred[base + k * NTHREADS];
    #pragma unroll
    for (int k = 0; k < PER_THREAD; ++k) m[k] = mask[base + k * NTHREADS];

    float a0 = 0.f, a1 = 0.f, a2 = 0.f, a3 = 0.f;
    #pragma unroll
    for (int k = 0; k < PER_THREAD; ++k) {
        a0 += fabsf(p[k].x - m[k].x);
        a1 += fabsf(p[k].y - m[k].y);
        a2 += fabsf(p[k].z - m[k].z);
        a3 += fabsf(p[k].w - m[k].w);
    }
    float acc = (a0 + a1) + (a2 + a3);

    // wave-64 shuffle reduce
    #pragma unroll
    for (int off = 32; off > 0; off >>= 1)
        acc += __shfl_down(acc, off, 64);

    __shared__ float s[NTHREADS / 64];
    const int lane = threadIdx.x & 63;
    const int wid  = threadIdx.x >> 6;
    if (lane == 0) s[wid] = acc;
    __syncthreads();
    if (threadIdx.x == 0) {
        float block_sum = (s[0] + s[1]) + (s[2] + s[3]);
        atomicAdd(out, block_sum * (1.0f / (float)N_TOTAL));
    }
}

extern "C" void kernel_launch(void* const* d_in, const int* in_sizes, int n_in,
                              void* d_out, int out_size, void* d_ws, size_t ws_size,
                              hipStream_t stream) {
    const float4* pred = (const float4*)d_in[0];
    const float4* mask = (const float4*)d_in[1];
    float* out = (float*)d_out;

    hipMemsetAsync(out, 0, sizeof(float), stream);
    abs_diff_mean<<<NBLOCKS, NTHREADS, 0, stream>>>(pred, mask, out);
}

// Round 6
// 26.434 us; speedup vs baseline: 1.6060x; 1.6060x over previous
//
#include <hip/hip_runtime.h>

// out[0] = mean(|pred - mask|) over 16Mi fp32 elements (the Gaussian-conv
// loop in the reference is dead code). Memory-bound streaming reduction.
//
// Round-6: revert to round-4's two-kernel structure (best: 26.08 us wall,
// main kernel ~6.1 TB/s effective = ~97% of achievable). Fusion attempts
// both lost: fence+counter (r3: L2 thrash, 88 us) and memset+atomicAdd
// (r5: serialized memset node + same-address cross-XCD atomics, 42 us).
// Micro-tweak: final_reduce is now one 64-lane wave with float4 loads,
// no LDS/barrier (it's launch-bound; shaves the tail slightly).

#define N_TOTAL (16u * 1024u * 1024u)   // 16,777,216 elements
#define NTHREADS 256
#define NBLOCKS  2048
#define PER_THREAD 8
#define CHUNK (NTHREADS * PER_THREAD)   // 2048 float4 per block per input

__global__ __launch_bounds__(NTHREADS) void abs_diff_partial(
    const float4* __restrict__ pred,
    const float4* __restrict__ mask,
    float* __restrict__ partial) {
    const unsigned base = blockIdx.x * CHUNK + threadIdx.x;

    float4 p[PER_THREAD], m[PER_THREAD];
    #pragma unroll
    for (int k = 0; k < PER_THREAD; ++k) p[k] = pred[base + k * NTHREADS];
    #pragma unroll
    for (int k = 0; k < PER_THREAD; ++k) m[k] = mask[base + k * NTHREADS];

    float a0 = 0.f, a1 = 0.f, a2 = 0.f, a3 = 0.f;
    #pragma unroll
    for (int k = 0; k < PER_THREAD; ++k) {
        a0 += fabsf(p[k].x - m[k].x);
        a1 += fabsf(p[k].y - m[k].y);
        a2 += fabsf(p[k].z - m[k].z);
        a3 += fabsf(p[k].w - m[k].w);
    }
    float acc = (a0 + a1) + (a2 + a3);

    // wave-64 shuffle reduce
    #pragma unroll
    for (int off = 32; off > 0; off >>= 1)
        acc += __shfl_down(acc, off, 64);

    __shared__ float s[NTHREADS / 64];
    const int lane = threadIdx.x & 63;
    const int wid  = threadIdx.x >> 6;
    if (lane == 0) s[wid] = acc;
    __syncthreads();
    if (threadIdx.x == 0)
        partial[blockIdx.x] = (s[0] + s[1]) + (s[2] + s[3]);  // fixed order
}

// One wave, no LDS: 2048 partials = 512 float4 = 8 per lane.
__global__ __launch_bounds__(64) void final_reduce(
    const float4* __restrict__ partial4, float* __restrict__ out) {
    float acc = 0.0f;
    #pragma unroll
    for (int k = 0; k < NBLOCKS / 4 / 64; ++k) {
        float4 v = partial4[threadIdx.x + k * 64];
        acc += (v.x + v.y) + (v.z + v.w);
    }
    #pragma unroll
    for (int off = 32; off > 0; off >>= 1)
        acc += __shfl_down(acc, off, 64);
    if (threadIdx.x == 0)
        out[0] = acc / (float)N_TOTAL;
}

extern "C" void kernel_launch(void* const* d_in, const int* in_sizes, int n_in,
                              void* d_out, int out_size, void* d_ws, size_t ws_size,
                              hipStream_t stream) {
    const float4* pred = (const float4*)d_in[0];
    const float4* mask = (const float4*)d_in[1];
    float* out = (float*)d_out;
    float* partial = (float*)d_ws;  // NBLOCKS floats = 8 KB scratch

    abs_diff_partial<<<NBLOCKS, NTHREADS, 0, stream>>>(pred, mask, partial);
    final_reduce<<<1, 64, 0, stream>>>((const float4*)partial, out);
}